// Round 3
// baseline (8108.480 us; speedup 1.0000x reference)
//
#include <hip/hip_runtime.h>

typedef unsigned short u16;
typedef __bf16 bf16x8 __attribute__((ext_vector_type(8)));
typedef float f32x4 __attribute__((ext_vector_type(4)));
typedef unsigned short u16x8 __attribute__((ext_vector_type(8)));

#define BB 1024
#define SS 256
#define DD 300
#define HH 150
#define GG 600
#define VV 21257
#define VPAD 21376      // 167*128
#define KSTR 320        // padded K stride for h1 / emb table
#define GSTR 608        // gates stride (600 rounded to 8)
#define WK 160          // padded Whh K stride

static __device__ __forceinline__ float bf2f(u16 u){
  unsigned v = ((unsigned)u) << 16;
  return __builtin_bit_cast(float, v);
}
static __device__ __forceinline__ u16 f2bf(float f){
  unsigned u = __builtin_bit_cast(unsigned, f);
  u = u + 0x7FFFu + ((u >> 16) & 1u);
  return (u16)(u >> 16);
}
static __device__ __forceinline__ float fsig(float x){
  return 1.0f / (1.0f + __expf(-x));
}
static __device__ __forceinline__ float ftanh_(float x){
  return 2.0f / (1.0f + __expf(-2.0f*x)) - 1.0f;
}

// ---------------- lengths from mask ----------------
__global__ void k_len(const int* __restrict__ mask, int* __restrict__ len){
  __shared__ int red[256];
  int b = blockIdx.x, t = threadIdx.x;
  red[t] = (mask[b*SS + t] != 0) ? 1 : 0;
  __syncthreads();
  for (int o = 128; o > 0; o >>= 1){
    if (t < o) red[t] += red[t+o];
    __syncthreads();
  }
  if (t == 0) len[b] = red[0];
}

// ---------------- deterministic rank sort by length (ascending) ----------------
__global__ void k_sort(const int* __restrict__ len, int* __restrict__ perm){
  __shared__ int L[1024];
  int b = threadIdx.x;
  int l = len[b];
  L[b] = l;
  __syncthreads();
  int r = 0;
  for (int j = 0; j < 1024; ++j){
    int lj = L[j];
    r += (lj < l) || (lj == l && j < b);
  }
  perm[r] = b;
}

// ---------------- weight pad/convert f32 -> bf16 ----------------
struct PrepW {
  const float* src[8];
  u16* dst[8];
  int R[8], C[8], DR[8], DC[8];
};
__global__ void k_prepw(PrepW p){
  int z = blockIdx.y;
  int n = p.DR[z]*p.DC[z];
  for (int i = blockIdx.x*256 + threadIdx.x; i < n; i += 800*256){
    int r = i / p.DC[z], c = i - r*p.DC[z];
    float v = (r < p.R[z] && c < p.C[z]) ? p.src[z][r*p.C[z] + c] : 0.f;
    p.dst[z][i] = f2bf(v);
  }
}
struct PrepB { const float* src[4]; float* dst[4]; };
__global__ void k_prepb(PrepB p){
  int z = blockIdx.y;
  int i = blockIdx.x*256 + threadIdx.x;
  if (i < 640) p.dst[z][i] = (i < GG) ? p.src[z][i] : 0.f;
}

// ---------------- embedding table pad/convert: [VPAD][KSTR] bf16, row 0 zeroed ----------------
__global__ void k_prepemb(const float* __restrict__ emb, u16* __restrict__ dst){
  long i = (long)blockIdx.x*256 + threadIdx.x;
  if (i >= (long)VPAD*KSTR) return;
  int r = (int)(i / KSTR), c = (int)(i - (long)r*KSTR);
  float v = (r >= 1 && r < VV && c < DD) ? emb[(size_t)r*DD + c] : 0.f;
  dst[i] = f2bf(v);
}

// ---------------- big GEMM: out[m][n] = bf16( sum_k A[m][k]*W[n][k] + bias[n] ) ----------------
// A: [*, KSTR] bf16, W: [640][KSTR] bf16 padded, out stride GSTR (write cols < 600 only)
// reg-double-buffered staging: loads for k-step kk+1 fly during MFMA of kk
__launch_bounds__(512, 2)
__global__ void k_gemm(const u16* __restrict__ A,
                       const u16* __restrict__ Wf, const u16* __restrict__ Wb,
                       const float* __restrict__ bsf, const float* __restrict__ bsb,
                       u16* __restrict__ of, u16* __restrict__ ob)
{
  const u16* W = blockIdx.z ? Wb : Wf;
  const float* bias = blockIdx.z ? bsb : bsf;
  u16* outp = blockIdx.z ? ob : of;

  __shared__ u16 Al[128*40];   // [128 rows][32 k] pad->40
  __shared__ u16 Bl[320*40];   // [320 n-rows][32 k] pad->40

  int tid = threadIdx.x;
  int l = tid & 63, w = tid >> 6;
  int lo = l & 15, hi = l >> 4;
  int wm = w >> 2, wn = w & 3;
  int m0 = blockIdx.x * 128;
  int n0 = blockIdx.y * 320;

  // staging assignments
  int ar = tid >> 2, ac = (tid & 3) * 8;
  const u16* Arow = A + (size_t)(m0 + ar)*KSTR + ac;
  bool bvld[3]; int brr[3], bcc[3];
  const u16* Brow[3];
  #pragma unroll
  for (int i = 0; i < 3; ++i){
    int ch = tid + i*512;
    bvld[i] = (ch < 1280);
    int r2 = bvld[i] ? (ch >> 2) : 0;
    brr[i] = r2; bcc[i] = (ch & 3) * 8;
    Brow[i] = W + (size_t)(n0 + r2)*KSTR + bcc[i];
  }

  u16x8 ra = *(const u16x8*)Arow;
  u16x8 rbv[3];
  #pragma unroll
  for (int i = 0; i < 3; ++i) if (bvld[i]) rbv[i] = *(const u16x8*)Brow[i];

  f32x4 zero = {0.f, 0.f, 0.f, 0.f};
  f32x4 acc[4][5];
  #pragma unroll
  for (int a = 0; a < 4; ++a)
    #pragma unroll
    for (int b = 0; b < 5; ++b) acc[a][b] = zero;

  for (int kk = 0; kk < 10; ++kk){
    __syncthreads();   // prior MFMA done reading LDS
    *(u16x8*)&Al[ar*40 + ac] = ra;
    #pragma unroll
    for (int i = 0; i < 3; ++i)
      if (bvld[i]) *(u16x8*)&Bl[brr[i]*40 + bcc[i]] = rbv[i];
    __syncthreads();
    if (kk < 9){
      int k1 = (kk+1)*32;
      ra = *(const u16x8*)(Arow + k1);
      #pragma unroll
      for (int i = 0; i < 3; ++i)
        if (bvld[i]) rbv[i] = *(const u16x8*)(Brow[i] + k1);
    }
    u16x8 av[4], bv[5];
    #pragma unroll
    for (int mt = 0; mt < 4; ++mt)
      av[mt] = *(const u16x8*)&Al[(wm*64 + mt*16 + lo)*40 + hi*8];
    #pragma unroll
    for (int nt = 0; nt < 5; ++nt)
      bv[nt] = *(const u16x8*)&Bl[(wn*80 + nt*16 + lo)*40 + hi*8];
    #pragma unroll
    for (int mt = 0; mt < 4; ++mt)
      #pragma unroll
      for (int nt = 0; nt < 5; ++nt)
        acc[mt][nt] = __builtin_amdgcn_mfma_f32_16x16x32_bf16(
            __builtin_bit_cast(bf16x8, av[mt]),
            __builtin_bit_cast(bf16x8, bv[nt]),
            acc[mt][nt], 0, 0, 0);
  }

  #pragma unroll
  for (int mt = 0; mt < 4; ++mt){
    #pragma unroll
    for (int nt = 0; nt < 5; ++nt){
      int col = n0 + wn*80 + nt*16 + lo;
      if (col < GG){
        float bsv = bias[col];
        #pragma unroll
        for (int r = 0; r < 4; ++r){
          int row = m0 + wm*64 + mt*16 + hi*4 + r;
          outp[(size_t)row*GSTR + col] = f2bf(acc[mt][nt][r] + bsv);
        }
      }
    }
  }
}

// ---------------- fused recurrence with gate prefetch ----------------
// L0=1: gate rows from token table (gf/gb = tables), writes h1 (chunk-local, stride KSTR)
// L0=0: gate rows from gate buffers (chunk-local), writes lastf (original batch order)
// grid: (tiles_in_chunk, 2); blockIdx.y = dir
template<int L0>
__launch_bounds__(512, 2)
__global__ void k_rec_t(const u16* __restrict__ gf, const u16* __restrict__ gb,
                        const u16* __restrict__ WhF, const u16* __restrict__ WhB,
                        const int* __restrict__ len, const int* __restrict__ perm, int co,
                        const int* __restrict__ x,
                        u16* __restrict__ h1, float* __restrict__ lastf)
{
  int dir  = blockIdx.y;
  int tile = blockIdx.x;
  const u16* xg  = dir ? gb : gf;
  const u16* Whh = dir ? WhB : WhF;

  __shared__ u16   hsm[16*168];   // bf16 h state [16][160 padK], stride 168
  __shared__ float csm[16*152];   // f32 c state
  __shared__ float gsm[16*612];   // f32 h-gate partials
  __shared__ int Ls[16], rbL[16], boS[16];

  int tid = threadIdx.x;
  int l = tid & 63, w = tid >> 6;
  int lo = l & 15, hi = l >> 4;

  // persistent Whh B-fragments: wave w owns n-tiles w*5..w*5+4
  u16x8 bw[5][5];
  #pragma unroll
  for (int j = 0; j < 5; ++j){
    int n0 = (w*5 + j)*16 + lo;
    #pragma unroll
    for (int ks = 0; ks < 5; ++ks)
      bw[j][ks] = *(const u16x8*)(Whh + (size_t)n0*WK + ks*32 + hi*8);
  }
  for (int i = tid; i < 16*168; i += 512) hsm[i] = 0;
  for (int i = tid; i < 16*152; i += 512) csm[i] = 0.f;
  if (tid < 16){
    int b = perm[co + tile*16 + tid];
    Ls[tid]  = len[b];
    rbL[tid] = (tile*16 + tid)*SS;
    boS[tid] = b;
  }
  __syncthreads();
  int maxL = Ls[15];   // ascending sort -> max of tile

  // static item decomposition: item = (sample i, hidden idx jj), 2400 items over 512 thr
  int iq[5], jq[5], Lq[5], rq[5], bq[5];
  bool vq[5];
  #pragma unroll
  for (int q = 0; q < 5; ++q){
    int it = tid + q*512;
    vq[q] = (it < 2400);
    int itc = vq[q] ? it : 0;
    int i = itc / 150;
    iq[q] = i; jq[q] = itc - i*150;
    Lq[q] = Ls[i];
    rq[q] = rbL[i];
    bq[q] = boS[i]*SS;
  }

  u16 gc[5][4], gn[5][4];
  int tokN[5];

  // prologue: gates(t=0) -> gc; for L0 also token(t=1) -> tokN
  #pragma unroll
  for (int q = 0; q < 5; ++q){
    int Li = Lq[q];
    int s0 = dir ? (Li-1) : 0;
    const u16* xr;
    if (L0){
      int tk = x[bq[q] + s0];
      xr = xg + (size_t)tk*GSTR;
    } else {
      xr = xg + (size_t)(rq[q] + s0)*GSTR;
    }
    gc[q][0] = xr[jq[q]];
    gc[q][1] = xr[150 + jq[q]];
    gc[q][2] = xr[300 + jq[q]];
    gc[q][3] = xr[450 + jq[q]];
    if (L0){
      int t1 = (1 < Li) ? 1 : (Li-1);
      int s1 = dir ? (Li-1-t1) : t1;
      tokN[q] = x[bq[q] + s1];
    }
  }

  for (int t = 0; t < maxL; ++t){
    // ---- prefetch gates for t+1 (addresses independent of h; clamped -> always safe)
    if (t+1 < maxL){
      #pragma unroll
      for (int q = 0; q < 5; ++q){
        int Li = Lq[q];
        int tt = (t+1 < Li) ? (t+1) : (Li-1);
        int s  = dir ? (Li-1-tt) : tt;
        const u16* xr;
        if (L0) xr = xg + (size_t)tokN[q]*GSTR;
        else    xr = xg + (size_t)(rq[q] + s)*GSTR;
        gn[q][0] = xr[jq[q]];
        gn[q][1] = xr[150 + jq[q]];
        gn[q][2] = xr[300 + jq[q]];
        gn[q][3] = xr[450 + jq[q]];
      }
      if (L0 && t+2 < maxL){
        #pragma unroll
        for (int q = 0; q < 5; ++q){
          int Li = Lq[q];
          int tt = (t+2 < Li) ? (t+2) : (Li-1);
          int s  = dir ? (Li-1-tt) : tt;
          tokN[q] = x[bq[q] + s];
        }
      }
    }

    // ---- MFMA: gsm = h @ Whh.T
    u16x8 av[5];
    #pragma unroll
    for (int ks = 0; ks < 5; ++ks)
      av[ks] = *(const u16x8*)&hsm[lo*168 + ks*32 + hi*8];
    f32x4 zero = {0.f,0.f,0.f,0.f};
    f32x4 acc[5];
    #pragma unroll
    for (int j = 0; j < 5; ++j) acc[j] = zero;
    #pragma unroll
    for (int ks = 0; ks < 5; ++ks)
      #pragma unroll
      for (int j = 0; j < 5; ++j)
        acc[j] = __builtin_amdgcn_mfma_f32_16x16x32_bf16(
            __builtin_bit_cast(bf16x8, av[ks]),
            __builtin_bit_cast(bf16x8, bw[j][ks]),
            acc[j], 0, 0, 0);
    #pragma unroll
    for (int j = 0; j < 5; ++j){
      int n = (w*5 + j)*16 + lo;
      if (n < GG){
        #pragma unroll
        for (int r = 0; r < 4; ++r)
          gsm[(hi*4 + r)*612 + n] = acc[j][r];
      }
    }
    __syncthreads();

    // ---- elementwise gates + state update (uses prefetched gc)
    #pragma unroll
    for (int q = 0; q < 5; ++q){
      int Li = Lq[q];
      if (vq[q] && t < Li){
        int i = iq[q], jj = jq[q];
        float pi = gsm[i*612 +        jj] + bf2f(gc[q][0]);
        float pf = gsm[i*612 + 150 +  jj] + bf2f(gc[q][1]);
        float pg = gsm[i*612 + 300 +  jj] + bf2f(gc[q][2]);
        float po = gsm[i*612 + 450 +  jj] + bf2f(gc[q][3]);
        float ig = fsig(pi), fg = fsig(pf), g2 = ftanh_(pg), og = fsig(po);
        float c  = fg * csm[i*152 + jj] + ig * g2;
        float hn = og * ftanh_(c);
        csm[i*152 + jj] = c;
        hsm[i*168 + jj] = f2bf(hn);
        if (L0){
          int s = dir ? (Li-1-t) : t;
          h1[(size_t)(rq[q] + s)*KSTR + dir*150 + jj] = f2bf(hn);
        } else {
          bool isl = dir ? (t == 0) : (t == Li - 1);
          if (isl) lastf[(size_t)boS[i]*304 + dir*150 + jj] = hn;
        }
      }
    }
    // ---- rotate prefetch regs
    #pragma unroll
    for (int q = 0; q < 5; ++q){
      gc[q][0] = gn[q][0]; gc[q][1] = gn[q][1];
      gc[q][2] = gn[q][2]; gc[q][3] = gn[q][3];
    }
    __syncthreads();
  }
}

// ---------------- classifier head (fp32): out = tanh(last@W1.T+b1)@W2.T+b2 ----------------
__global__ void k_cls(const float* __restrict__ lastf,
                      const float* __restrict__ W1, const float* __restrict__ b1,
                      const float* __restrict__ W2, const float* __restrict__ b2,
                      float* __restrict__ out)
{
  __shared__ float inb[16][304];
  __shared__ float mid[16][304];
  int r0 = blockIdx.x * 16;
  int tid = threadIdx.x;
  for (int i = tid; i < 16*300; i += 256){
    int r = i / 300, c = i - r*300;
    inb[r][c] = lastf[(size_t)(r0+r)*304 + c];
  }
  __syncthreads();
  for (int i = tid; i < 4800; i += 256){
    int r = i / 300, c = i - r*300;
    float a = b1[c];
    const float* wr = W1 + (size_t)c*300;
    for (int k = 0; k < 300; ++k) a += inb[r][k] * wr[k];
    mid[r][c] = ftanh_(a);
  }
  __syncthreads();
  for (int i = tid; i < 4800; i += 256){
    int r = i / 300, c = i - r*300;
    float a = b2[c];
    const float* wr = W2 + (size_t)c*300;
    for (int k = 0; k < 300; ++k) a += mid[r][k] * wr[k];
    out[(size_t)(r0+r)*300 + c] = a;
  }
}

extern "C" void kernel_launch(void* const* d_in, const int* in_sizes, int n_in,
                              void* d_out, int out_size, void* d_ws, size_t ws_size,
                              hipStream_t stream)
{
  const int*   x    = (const int*)d_in[0];
  const int*   mask = (const int*)d_in[1];
  const float* emb  = (const float*)d_in[2];
  const float* Wih[4] = {(const float*)d_in[3], (const float*)d_in[6],
                         (const float*)d_in[9], (const float*)d_in[12]};
  const float* Whh[4] = {(const float*)d_in[4], (const float*)d_in[7],
                         (const float*)d_in[10], (const float*)d_in[13]};
  const float* bs[4]  = {(const float*)d_in[5], (const float*)d_in[8],
                         (const float*)d_in[11], (const float*)d_in[14]};
  const float* W1 = (const float*)d_in[15];
  const float* b1 = (const float*)d_in[16];
  const float* W2 = (const float*)d_in[17];
  const float* b2 = (const float*)d_in[18];
  float* out = (float*)d_out;

  char* p = (char*)d_ws;
  auto alloc = [&](size_t bytes){ char* r = p; p += (bytes + 255) & ~(size_t)255; return r; };

  // fixed allocations
  u16 *WihP[4], *WhhP[4];
  for (int i = 0; i < 4; ++i){
    WihP[i] = (u16*)alloc(640*320*2);
    WhhP[i] = (u16*)alloc(640*160*2);
  }
  float* biasP[4];
  for (int i = 0; i < 4; ++i) biasP[i] = (float*)alloc(640*4);
  int* len  = (int*)alloc(1024*4);
  int* perm = (int*)alloc(1024*4);
  float* lastf = (float*)alloc((size_t)1024*304*4);
  u16* embP = (u16*)alloc((size_t)VPAD*KSTR*2);          // 13.7 MB
  u16* tabF = (u16*)alloc((size_t)VPAD*GSTR*2);          // 26 MB
  u16* tabB = (u16*)alloc((size_t)VPAD*GSTR*2);          // 26 MB
  size_t fixed_end = (size_t)(p - (char*)d_ws);

  // choose chunk count so variable buffers fit in ws_size
  const size_t per_sample = (size_t)SS*KSTR*2 + 2*(size_t)SS*GSTR*2;  // 786432 B
  int nc = 32;
  const int cands[6] = {1, 2, 4, 8, 16, 32};
  for (int ci = 0; ci < 6; ++ci){
    size_t need = fixed_end + (size_t)(BB / cands[ci]) * per_sample + 8192;
    if (need <= ws_size){ nc = cands[ci]; break; }
  }
  const int Bc = BB / nc;
  const int Mc = Bc * SS;

  u16* h1    = (u16*)alloc((size_t)Mc*KSTR*2);
  u16* gatef = (u16*)alloc((size_t)Mc*GSTR*2);
  u16* gateb = (u16*)alloc((size_t)Mc*GSTR*2);

  // h1 pad cols (300..319) must be zero for the layer-1 GEMM K-sum; zero whole buf once
  hipMemsetAsync(h1, 0, (size_t)Mc*KSTR*2, stream);

  k_len <<<dim3(1024), dim3(256), 0, stream>>>(mask, len);
  k_sort<<<dim3(1),    dim3(1024),0, stream>>>(len, perm);

  PrepW pw;
  for (int i = 0; i < 4; ++i){
    pw.src[i] = Wih[i]; pw.dst[i] = WihP[i];
    pw.R[i] = GG; pw.C[i] = DD; pw.DR[i] = 640; pw.DC[i] = KSTR;
    pw.src[4+i] = Whh[i]; pw.dst[4+i] = WhhP[i];
    pw.R[4+i] = GG; pw.C[4+i] = HH; pw.DR[4+i] = 640; pw.DC[4+i] = WK;
  }
  k_prepw<<<dim3(800, 8), dim3(256), 0, stream>>>(pw);

  PrepB pb;
  for (int i = 0; i < 4; ++i){ pb.src[i] = bs[i]; pb.dst[i] = biasP[i]; }
  k_prepb<<<dim3(3, 4), dim3(256), 0, stream>>>(pb);

  k_prepemb<<<dim3((VPAD*KSTR + 255)/256), dim3(256), 0, stream>>>(emb, embP);

  // token -> layer-0 x-gate tables (fwd & bwd), bias folded in
  k_gemm<<<dim3(VPAD/128, 2, 2), dim3(512), 0, stream>>>(embP, WihP[0], WihP[1],
                                                         biasP[0], biasP[1], tabF, tabB);

  for (int c = 0; c < nc; ++c){
    int co = c * Bc;
    // layer 0: recurrence straight from the token table
    k_rec_t<1><<<dim3(Bc/16, 2), dim3(512), 0, stream>>>(tabF, tabB, WhhP[0], WhhP[1],
                                                         len, perm, co, x, h1, nullptr);
    // layer 1: x-gate GEMM over chunk h1, then recurrence
    k_gemm<<<dim3(Mc/128, 2, 2), dim3(512), 0, stream>>>(h1, WihP[2], WihP[3],
                                                         biasP[2], biasP[3], gatef, gateb);
    k_rec_t<0><<<dim3(Bc/16, 2), dim3(512), 0, stream>>>(gatef, gateb, WhhP[2], WhhP[3],
                                                         len, perm, co, x, nullptr, lastf);
  }

  k_cls<<<dim3(64), dim3(256), 0, stream>>>(lastf, W1, b1, W2, b2, out);
}

// Round 4
// 4400.607 us; speedup vs baseline: 1.8426x; 1.8426x over previous
//
#include <hip/hip_runtime.h>

typedef unsigned short u16;
typedef __bf16 bf16x8 __attribute__((ext_vector_type(8)));
typedef float f32x4 __attribute__((ext_vector_type(4)));
typedef float f4 __attribute__((ext_vector_type(4)));
typedef unsigned short u16x8 __attribute__((ext_vector_type(8)));

#define BB 1024
#define SS 256
#define DD 300
#define HH 150
#define GG 600
#define VV 21257
#define VPAD 21376      // 167*128
#define KSTR 320        // padded K stride for h1 / emb table
#define GSTR 600        // gates row stride
#define WK 160          // padded Whh K stride

static __device__ __forceinline__ float bf2f(u16 u){
  unsigned v = ((unsigned)u) << 16;
  return __builtin_bit_cast(float, v);
}
static __device__ __forceinline__ u16 f2bf(float f){
  unsigned u = __builtin_bit_cast(unsigned, f);
  u = u + 0x7FFFu + ((u >> 16) & 1u);
  return (u16)(u >> 16);
}
static __device__ __forceinline__ float fsig(float x){
  return __builtin_amdgcn_rcpf(1.0f + __expf(-x));
}
static __device__ __forceinline__ float ftanh_(float x){
  return 2.0f * __builtin_amdgcn_rcpf(1.0f + __expf(-2.0f*x)) - 1.0f;
}

// ---------------- lengths from mask ----------------
__global__ void k_len(const int* __restrict__ mask, int* __restrict__ len){
  __shared__ int red[256];
  int b = blockIdx.x, t = threadIdx.x;
  red[t] = (mask[b*SS + t] != 0) ? 1 : 0;
  __syncthreads();
  for (int o = 128; o > 0; o >>= 1){
    if (t < o) red[t] += red[t+o];
    __syncthreads();
  }
  if (t == 0) len[b] = red[0];
}

// ---------------- deterministic rank sort by length (ascending) ----------------
__global__ void k_sort(const int* __restrict__ len, int* __restrict__ perm){
  __shared__ int L[1024];
  int b = threadIdx.x;
  int l = len[b];
  L[b] = l;
  __syncthreads();
  int r = 0;
  for (int j = 0; j < 1024; ++j){
    int lj = L[j];
    r += (lj < l) || (lj == l && j < b);
  }
  perm[r] = b;
}

// ---------------- weight pad/convert f32 -> bf16 ----------------
struct PrepW {
  const float* src[8];
  u16* dst[8];
  int R[8], C[8], DR[8], DC[8];
};
__global__ void k_prepw(PrepW p){
  int z = blockIdx.y;
  int n = p.DR[z]*p.DC[z];
  for (int i = blockIdx.x*256 + threadIdx.x; i < n; i += 800*256){
    int r = i / p.DC[z], c = i - r*p.DC[z];
    float v = (r < p.R[z] && c < p.C[z]) ? p.src[z][r*p.C[z] + c] : 0.f;
    p.dst[z][i] = f2bf(v);
  }
}
struct PrepB { const float* src[4]; float* dst[4]; };
__global__ void k_prepb(PrepB p){
  int z = blockIdx.y;
  int i = blockIdx.x*256 + threadIdx.x;
  if (i < 640) p.dst[z][i] = (i < GG) ? p.src[z][i] : 0.f;
}

// ---------------- embedding table pad/convert: [VPAD][KSTR] bf16, row 0 zeroed ----------------
__global__ void k_prepemb(const float* __restrict__ emb, u16* __restrict__ dst){
  long i = (long)blockIdx.x*256 + threadIdx.x;
  if (i >= (long)VPAD*KSTR) return;
  int r = (int)(i / KSTR), c = (int)(i - (long)r*KSTR);
  float v = (r >= 1 && r < VV && c < DD) ? emb[(size_t)r*DD + c] : 0.f;
  dst[i] = f2bf(v);
}

// ---------------- big GEMM: out[m][n] = bf16( sum_k A[m][k]*W[n][k] + bias[n] ) ----------------
__launch_bounds__(512, 2)
__global__ void k_gemm(const u16* __restrict__ A,
                       const u16* __restrict__ Wf, const u16* __restrict__ Wb,
                       const float* __restrict__ bsf, const float* __restrict__ bsb,
                       u16* __restrict__ of, u16* __restrict__ ob)
{
  const u16* W = blockIdx.z ? Wb : Wf;
  const float* bias = blockIdx.z ? bsb : bsf;
  u16* outp = blockIdx.z ? ob : of;

  __shared__ u16 Al[128*40];
  __shared__ u16 Bl[320*40];

  int tid = threadIdx.x;
  int l = tid & 63, w = tid >> 6;
  int lo = l & 15, hi = l >> 4;
  int wm = w >> 2, wn = w & 3;
  int m0 = blockIdx.x * 128;
  int n0 = blockIdx.y * 320;

  int ar = tid >> 2, ac = (tid & 3) * 8;
  const u16* Arow = A + (size_t)(m0 + ar)*KSTR + ac;
  bool bvld[3]; int brr[3], bcc[3];
  const u16* Brow[3];
  #pragma unroll
  for (int i = 0; i < 3; ++i){
    int ch = tid + i*512;
    bvld[i] = (ch < 1280);
    int r2 = bvld[i] ? (ch >> 2) : 0;
    brr[i] = r2; bcc[i] = (ch & 3) * 8;
    Brow[i] = W + (size_t)(n0 + r2)*KSTR + bcc[i];
  }

  u16x8 ra = *(const u16x8*)Arow;
  u16x8 rbv[3];
  #pragma unroll
  for (int i = 0; i < 3; ++i) if (bvld[i]) rbv[i] = *(const u16x8*)Brow[i];

  f32x4 zero = {0.f, 0.f, 0.f, 0.f};
  f32x4 acc[4][5];
  #pragma unroll
  for (int a = 0; a < 4; ++a)
    #pragma unroll
    for (int b = 0; b < 5; ++b) acc[a][b] = zero;

  for (int kk = 0; kk < 10; ++kk){
    __syncthreads();
    *(u16x8*)&Al[ar*40 + ac] = ra;
    #pragma unroll
    for (int i = 0; i < 3; ++i)
      if (bvld[i]) *(u16x8*)&Bl[brr[i]*40 + bcc[i]] = rbv[i];
    __syncthreads();
    if (kk < 9){
      int k1 = (kk+1)*32;
      ra = *(const u16x8*)(Arow + k1);
      #pragma unroll
      for (int i = 0; i < 3; ++i)
        if (bvld[i]) rbv[i] = *(const u16x8*)(Brow[i] + k1);
    }
    u16x8 av[4], bv[5];
    #pragma unroll
    for (int mt = 0; mt < 4; ++mt)
      av[mt] = *(const u16x8*)&Al[(wm*64 + mt*16 + lo)*40 + hi*8];
    #pragma unroll
    for (int nt = 0; nt < 5; ++nt)
      bv[nt] = *(const u16x8*)&Bl[(wn*80 + nt*16 + lo)*40 + hi*8];
    #pragma unroll
    for (int mt = 0; mt < 4; ++mt)
      #pragma unroll
      for (int nt = 0; nt < 5; ++nt)
        acc[mt][nt] = __builtin_amdgcn_mfma_f32_16x16x32_bf16(
            __builtin_bit_cast(bf16x8, av[mt]),
            __builtin_bit_cast(bf16x8, bv[nt]),
            acc[mt][nt], 0, 0, 0);
  }

  #pragma unroll
  for (int mt = 0; mt < 4; ++mt){
    #pragma unroll
    for (int nt = 0; nt < 5; ++nt){
      int col = n0 + wn*80 + nt*16 + lo;
      if (col < GG){
        float bsv = bias[col];
        #pragma unroll
        for (int r = 0; r < 4; ++r){
          int row = m0 + wm*64 + mt*16 + hi*4 + r;
          outp[(size_t)row*GSTR + col] = f2bf(acc[mt][nt][r] + bsv);
        }
      }
    }
  }
}

// ---------------- fused recurrence v2: in-register gates, 1 raw barrier/step ----------------
// 640 threads = 10 waves; wave w owns jj in [16w, 16w+16); lane holds all 4 gates of its jj.
// C-layout of 16x16x32 MFMA: col = lane&15 (jj slot), row = (lane>>4)*4 + reg (sample).
#define REC_STEP(T, PB, GB)                                                     \
  {                                                                             \
    f32x4 acc0 = {0,0,0,0}, acc1 = {0,0,0,0}, acc2 = {0,0,0,0}, acc3 = {0,0,0,0}; \
    _Pragma("unroll")                                                           \
    for (int ks = 0; ks < 5; ++ks){                                             \
      u16x8 a_ = *(const u16x8*)&hsm[PB][lo*168 + ks*32 + hi*8];                \
      acc0 = __builtin_amdgcn_mfma_f32_16x16x32_bf16(                           \
          __builtin_bit_cast(bf16x8, a_), __builtin_bit_cast(bf16x8, bw[0][ks]), acc0, 0,0,0); \
      acc1 = __builtin_amdgcn_mfma_f32_16x16x32_bf16(                           \
          __builtin_bit_cast(bf16x8, a_), __builtin_bit_cast(bf16x8, bw[1][ks]), acc1, 0,0,0); \
      acc2 = __builtin_amdgcn_mfma_f32_16x16x32_bf16(                           \
          __builtin_bit_cast(bf16x8, a_), __builtin_bit_cast(bf16x8, bw[2][ks]), acc2, 0,0,0); \
      acc3 = __builtin_amdgcn_mfma_f32_16x16x32_bf16(                           \
          __builtin_bit_cast(bf16x8, a_), __builtin_bit_cast(bf16x8, bw[3][ks]), acc3, 0,0,0); \
    }                                                                           \
    _Pragma("unroll")                                                           \
    for (int r = 0; r < 4; ++r){                                                \
      if (jv && (T) < Lr[r]){                                                   \
        float pi = acc0[r] + bf2f(GB[r][0]);                                    \
        float pf = acc1[r] + bf2f(GB[r][1]);                                    \
        float pg = acc2[r] + bf2f(GB[r][2]);                                    \
        float po = acc3[r] + bf2f(GB[r][3]);                                    \
        float ig = fsig(pi), fg = fsig(pf), g2 = ftanh_(pg), og = fsig(po);     \
        float cc = fg*cst[r] + ig*g2;  cst[r] = cc;                             \
        float hn = og * ftanh_(cc);                                             \
        u16 hb = f2bf(hn);                                                      \
        hsm[(PB)^1][(hi*4+r)*168 + jj] = hb;                                    \
        if (L0){                                                                \
          int s_ = dir ? (Lr[r]-1-(T)) : (T);                                   \
          h1[(size_t)(rowb[r]+s_)*KSTR + dir*150 + jj] = hb;                    \
        } else {                                                                \
          bool isl = dir ? ((T)==0) : ((T)==Lr[r]-1);                           \
          if (isl) lastf[(size_t)bo2[r]*304 + dir*150 + jj] = hn;               \
        }                                                                       \
      }                                                                         \
    }                                                                           \
    if ((T)+2 < maxL){                                                          \
      _Pragma("unroll")                                                         \
      for (int r = 0; r < 4; ++r){                                              \
        int Li = Lr[r];                                                         \
        int tt = ((T)+2 < Li) ? (T)+2 : (Li-1);                                 \
        int s_ = dir ? (Li-1-tt) : tt;                                          \
        const u16* xr;                                                          \
        if (L0) xr = xg + (size_t)tks[(hi*4+r)*256 + s_]*GSTR;                  \
        else    xr = xg + (size_t)(rowb[r]+s_)*GSTR;                            \
        _Pragma("unroll")                                                       \
        for (int g = 0; g < 4; ++g) GB[r][g] = xr[g*150 + jjc];                 \
      }                                                                         \
    }                                                                           \
    __builtin_amdgcn_sched_barrier(0);                                          \
    asm volatile("s_waitcnt lgkmcnt(0)" ::: "memory");                          \
    __builtin_amdgcn_s_barrier();                                               \
    __builtin_amdgcn_sched_barrier(0);                                          \
  }

#define PRO_LOAD(GB, PP)                                                        \
  _Pragma("unroll")                                                             \
  for (int r = 0; r < 4; ++r){                                                  \
    int Li = Lr[r];                                                             \
    int tt = ((PP) < Li) ? (PP) : (Li-1);                                       \
    int s_ = dir ? (Li-1-tt) : tt;                                              \
    const u16* xr;                                                              \
    if (L0) xr = xg + (size_t)tks[(hi*4+r)*256 + s_]*GSTR;                      \
    else    xr = xg + (size_t)(rowb[r]+s_)*GSTR;                                \
    _Pragma("unroll")                                                           \
    for (int g = 0; g < 4; ++g) GB[r][g] = xr[g*150 + jjc];                     \
  }

template<int L0>
__launch_bounds__(640, 1)
__global__ void k_rec2(const u16* __restrict__ gf, const u16* __restrict__ gb,
                       const u16* __restrict__ WhF, const u16* __restrict__ WhB,
                       const int* __restrict__ len, const int* __restrict__ perm, int co,
                       const int* __restrict__ x,
                       u16* __restrict__ h1, float* __restrict__ lastf, int dirSel)
{
  int dir  = (dirSel < 0) ? (int)blockIdx.y : dirSel;
  int tile = blockIdx.x;
  const u16* xg  = dir ? gb : gf;
  const u16* Whh = dir ? WhB : WhF;

  __shared__ u16 hsm[2][16*168];   // bf16 h dbuf [16 samples][160 padK] stride 168
  __shared__ u16 tks[16*256];      // tokens (L0 only)
  __shared__ int Ls[16], rbL[16], boS[16];

  int tid = threadIdx.x;
  int l = tid & 63, w = tid >> 6;   // w = jj-group 0..9
  int lo = l & 15, hi = l >> 4;
  int jj = w*16 + lo;               // 0..159
  bool jv = (jj < HH);
  int jjc = jv ? jj : 0;

  // B fragments: acc tile g covers Whh rows g*150 + jj  (row < 610 < 640, padded)
  u16x8 bw[4][5];
  #pragma unroll
  for (int g = 0; g < 4; ++g)
    #pragma unroll
    for (int ks = 0; ks < 5; ++ks)
      bw[g][ks] = *(const u16x8*)(Whh + (size_t)(g*150 + jj)*WK + ks*32 + hi*8);

  for (int i = tid; i < 2*16*168; i += 640) ((u16*)hsm)[i] = 0;
  if (tid < 16){
    int b = perm[co + tile*16 + tid];
    Ls[tid]  = len[b];
    rbL[tid] = (tile*16 + tid)*SS;
    boS[tid] = b;
  }
  __syncthreads();
  if (L0){
    for (int idx = tid; idx < 16*256; idx += 640){
      int i = idx >> 8, s = idx & 255;
      tks[idx] = (u16)x[boS[i]*SS + s];
    }
  }
  __syncthreads();

  int maxL = Ls[15];
  int Lr[4], rowb[4], bo2[4];
  #pragma unroll
  for (int r = 0; r < 4; ++r){
    int i = hi*4 + r;
    Lr[r] = Ls[i]; rowb[r] = rbL[i]; bo2[r] = boS[i];
  }

  float cst[4] = {0.f, 0.f, 0.f, 0.f};
  u16 gA[4][4], gB[4][4];
  PRO_LOAD(gA, 0)
  PRO_LOAD(gB, 1)

  for (int t = 0; t < maxL; t += 2){
    REC_STEP(t, 0, gA)
    if (t + 1 < maxL){
      REC_STEP(t+1, 1, gB)
    }
  }
}

// ---------------- classifier head (fp32, float4): out = tanh(last@W1.T+b1)@W2.T+b2 ----------------
__global__ void k_cls(const float* __restrict__ lastf,
                      const float* __restrict__ W1, const float* __restrict__ b1,
                      const float* __restrict__ W2, const float* __restrict__ b2,
                      float* __restrict__ out)
{
  __shared__ float inb[8][304];
  __shared__ float mid[8][304];
  int r0 = blockIdx.x * 8, tid = threadIdx.x;
  for (int i = tid; i < 8*76; i += 256){
    int r = i / 76, c4 = i - r*76;
    ((f4*)&inb[r][0])[c4] = ((const f4*)(lastf + (size_t)(r0+r)*304))[c4];
  }
  __syncthreads();
  for (int item = tid; item < 2400; item += 256){
    int r = item / 300, c = item - r*300;
    const f4* wr = (const f4*)(W1 + (size_t)c*300);
    const f4* xr = (const f4*)&inb[r][0];
    f4 a0 = {0,0,0,0}, a1 = {0,0,0,0}, a2 = {0,0,0,0};
    for (int k = 0; k < 75; k += 3){
      a0 += xr[k]   * wr[k];
      a1 += xr[k+1] * wr[k+1];
      a2 += xr[k+2] * wr[k+2];
    }
    f4 s4 = a0 + a1 + a2;
    float a = s4[0] + s4[1] + s4[2] + s4[3] + b1[c];
    mid[r][c] = ftanh_(a);
  }
  __syncthreads();
  for (int item = tid; item < 2400; item += 256){
    int r = item / 300, c = item - r*300;
    const f4* wr = (const f4*)(W2 + (size_t)c*300);
    const f4* xr = (const f4*)&mid[r][0];
    f4 a0 = {0,0,0,0}, a1 = {0,0,0,0}, a2 = {0,0,0,0};
    for (int k = 0; k < 75; k += 3){
      a0 += xr[k]   * wr[k];
      a1 += xr[k+1] * wr[k+1];
      a2 += xr[k+2] * wr[k+2];
    }
    f4 s4 = a0 + a1 + a2;
    out[(size_t)(r0+r)*300 + c] = s4[0] + s4[1] + s4[2] + s4[3] + b2[c];
  }
}

extern "C" void kernel_launch(void* const* d_in, const int* in_sizes, int n_in,
                              void* d_out, int out_size, void* d_ws, size_t ws_size,
                              hipStream_t stream)
{
  const int*   x    = (const int*)d_in[0];
  const int*   mask = (const int*)d_in[1];
  const float* emb  = (const float*)d_in[2];
  const float* Wih[4] = {(const float*)d_in[3], (const float*)d_in[6],
                         (const float*)d_in[9], (const float*)d_in[12]};
  const float* Whh[4] = {(const float*)d_in[4], (const float*)d_in[7],
                         (const float*)d_in[10], (const float*)d_in[13]};
  const float* bs[4]  = {(const float*)d_in[5], (const float*)d_in[8],
                         (const float*)d_in[11], (const float*)d_in[14]};
  const float* W1 = (const float*)d_in[15];
  const float* b1 = (const float*)d_in[16];
  const float* W2 = (const float*)d_in[17];
  const float* b2 = (const float*)d_in[18];
  float* out = (float*)d_out;

  char* p = (char*)d_ws;
  auto alloc = [&](size_t bytes){ char* r = p; p += (bytes + 255) & ~(size_t)255; return r; };

  // fixed allocations (~70 MB incl. token->gate tables)
  u16 *WihP[4], *WhhP[4];
  for (int i = 0; i < 4; ++i){
    WihP[i] = (u16*)alloc(640*320*2);
    WhhP[i] = (u16*)alloc(640*160*2);
  }
  float* biasP[4];
  for (int i = 0; i < 4; ++i) biasP[i] = (float*)alloc(640*4);
  int* len  = (int*)alloc(1024*4);
  int* perm = (int*)alloc(1024*4);
  float* lastf = (float*)alloc((size_t)1024*304*4);
  u16* embP = (u16*)alloc((size_t)VPAD*KSTR*2);
  u16* tabF = (u16*)alloc((size_t)VPAD*GSTR*2);
  u16* tabB = (u16*)alloc((size_t)VPAD*GSTR*2);
  size_t fixed_end = (size_t)(p - (char*)d_ws);

  // variable: h1 (chunk) + ONE single-direction gate buffer (L1 split by dir)
  const size_t per_sample = (size_t)SS*KSTR*2 + (size_t)SS*GSTR*2;  // 471040 B
  int nc = 32;
  const int cands[6] = {1, 2, 4, 8, 16, 32};
  for (int ci = 0; ci < 6; ++ci){
    size_t need = fixed_end + (size_t)(BB / cands[ci]) * per_sample + (1u<<20);
    if (need <= ws_size){ nc = cands[ci]; break; }
  }
  const int Bc = BB / nc;
  const int Mc = Bc * SS;

  u16* h1   = (u16*)alloc((size_t)Mc*KSTR*2);
  u16* gate = (u16*)alloc((size_t)Mc*GSTR*2);

  hipMemsetAsync(h1, 0, (size_t)Mc*KSTR*2, stream);   // pad cols 300..319 must be 0

  k_len <<<dim3(1024), dim3(256), 0, stream>>>(mask, len);
  k_sort<<<dim3(1),    dim3(1024),0, stream>>>(len, perm);

  PrepW pw;
  for (int i = 0; i < 4; ++i){
    pw.src[i] = Wih[i]; pw.dst[i] = WihP[i];
    pw.R[i] = GG; pw.C[i] = DD; pw.DR[i] = 640; pw.DC[i] = KSTR;
    pw.src[4+i] = Whh[i]; pw.dst[4+i] = WhhP[i];
    pw.R[4+i] = GG; pw.C[4+i] = HH; pw.DR[4+i] = 640; pw.DC[4+i] = WK;
  }
  k_prepw<<<dim3(800, 8), dim3(256), 0, stream>>>(pw);

  PrepB pb;
  for (int i = 0; i < 4; ++i){ pb.src[i] = bs[i]; pb.dst[i] = biasP[i]; }
  k_prepb<<<dim3(3, 4), dim3(256), 0, stream>>>(pb);

  k_prepemb<<<dim3((VPAD*KSTR + 255)/256), dim3(256), 0, stream>>>(emb, embP);

  // token -> layer-0 x-gate tables (both dirs), bias folded in
  k_gemm<<<dim3(VPAD/128, 2, 2), dim3(512), 0, stream>>>(embP, WihP[0], WihP[1],
                                                         biasP[0], biasP[1], tabF, tabB);

  for (int c = 0; c < nc; ++c){
    int co = c * Bc;
    // layer 0: both directions from the token tables
    k_rec2<1><<<dim3(Bc/16, 2), dim3(640), 0, stream>>>(tabF, tabB, WhhP[0], WhhP[1],
                                                        len, perm, co, x, h1, nullptr, -1);
    // layer 1: per direction: x-gate GEMM then recurrence
    for (int d = 0; d < 2; ++d){
      k_gemm<<<dim3(Mc/128, 2, 1), dim3(512), 0, stream>>>(h1, WihP[2+d], WihP[2+d],
                                                           biasP[2+d], biasP[2+d], gate, gate);
      k_rec2<0><<<dim3(Bc/16, 1), dim3(640), 0, stream>>>(gate, gate, WhhP[2], WhhP[3],
                                                          len, perm, co, x, nullptr, lastf, d);
    }
  }

  k_cls<<<dim3(128), dim3(256), 0, stream>>>(lastf, W1, b1, W2, b2, out);
}

// Round 5
// 3646.140 us; speedup vs baseline: 2.2239x; 1.2069x over previous
//
#include <hip/hip_runtime.h>

typedef unsigned short u16;
typedef __bf16 bf16x8 __attribute__((ext_vector_type(8)));
typedef float f32x4 __attribute__((ext_vector_type(4)));
typedef float f4 __attribute__((ext_vector_type(4)));
typedef unsigned short u16x8 __attribute__((ext_vector_type(8)));
typedef unsigned short u16x4 __attribute__((ext_vector_type(4)));

#define BB 1024
#define SS 256
#define DD 300
#define HH 150
#define GG 600
#define VV 21257
#define VPAD 21376      // 167*128
#define KSTR 320        // padded K stride for h1 / emb table
#define GSTR 600        // gate row stride (u16), layout [jj][4 gates] interleaved
#define WK 160          // padded Whh K stride

static __device__ __forceinline__ float bf2f(u16 u){
  unsigned v = ((unsigned)u) << 16;
  return __builtin_bit_cast(float, v);
}
static __device__ __forceinline__ u16 f2bf(float f){
  unsigned u = __builtin_bit_cast(unsigned, f);
  u = u + 0x7FFFu + ((u >> 16) & 1u);
  return (u16)(u >> 16);
}
static __device__ __forceinline__ float fsig(float x){
  return __builtin_amdgcn_rcpf(1.0f + __expf(-x));
}
static __device__ __forceinline__ float ftanh_(float x){
  return 2.0f * __builtin_amdgcn_rcpf(1.0f + __expf(-2.0f*x)) - 1.0f;
}

// ---------------- lengths from mask ----------------
__global__ void k_len(const int* __restrict__ mask, int* __restrict__ len){
  __shared__ int red[256];
  int b = blockIdx.x, t = threadIdx.x;
  red[t] = (mask[b*SS + t] != 0) ? 1 : 0;
  __syncthreads();
  for (int o = 128; o > 0; o >>= 1){
    if (t < o) red[t] += red[t+o];
    __syncthreads();
  }
  if (t == 0) len[b] = red[0];
}

// ---------------- deterministic rank sort by length (ascending) ----------------
__global__ void k_sort(const int* __restrict__ len, int* __restrict__ perm){
  __shared__ int L[1024];
  int b = threadIdx.x;
  int l = len[b];
  L[b] = l;
  __syncthreads();
  int r = 0;
  for (int j = 0; j < 1024; ++j){
    int lj = L[j];
    r += (lj < l) || (lj == l && j < b);
  }
  perm[r] = b;
}

// ---------------- weight pad/convert f32 -> bf16 ----------------
struct PrepW {
  const float* src[8];
  u16* dst[8];
  int R[8], C[8], DR[8], DC[8];
};
__global__ void k_prepw(PrepW p){
  int z = blockIdx.y;
  int n = p.DR[z]*p.DC[z];
  for (int i = blockIdx.x*256 + threadIdx.x; i < n; i += 800*256){
    int r = i / p.DC[z], c = i - r*p.DC[z];
    float v = (r < p.R[z] && c < p.C[z]) ? p.src[z][r*p.C[z] + c] : 0.f;
    p.dst[z][i] = f2bf(v);
  }
}
struct PrepB { const float* src[4]; float* dst[4]; };
__global__ void k_prepb(PrepB p){
  int z = blockIdx.y;
  int i = blockIdx.x*256 + threadIdx.x;
  if (i < 640) p.dst[z][i] = (i < GG) ? p.src[z][i] : 0.f;
}

// ---------------- embedding table pad/convert: [VPAD][KSTR] bf16, row 0 zeroed ----------------
__global__ void k_prepemb(const float* __restrict__ emb, u16* __restrict__ dst){
  long i = (long)blockIdx.x*256 + threadIdx.x;
  if (i >= (long)VPAD*KSTR) return;
  int r = (int)(i / KSTR), c = (int)(i - (long)r*KSTR);
  float v = (r >= 1 && r < VV && c < DD) ? emb[(size_t)r*DD + c] : 0.f;
  dst[i] = f2bf(v);
}

// ---------------- big GEMM: gates[m][jj*4+g] = bf16( sum_k A[m][k]*W[g*150+jj][k] + bias ) ----
__launch_bounds__(512, 2)
__global__ void k_gemm(const u16* __restrict__ A,
                       const u16* __restrict__ Wf, const u16* __restrict__ Wb,
                       const float* __restrict__ bsf, const float* __restrict__ bsb,
                       u16* __restrict__ of, u16* __restrict__ ob)
{
  const u16* W = blockIdx.z ? Wb : Wf;
  const float* bias = blockIdx.z ? bsb : bsf;
  u16* outp = blockIdx.z ? ob : of;

  __shared__ u16 Al[128*40];
  __shared__ u16 Bl[320*40];

  int tid = threadIdx.x;
  int l = tid & 63, w = tid >> 6;
  int lo = l & 15, hi = l >> 4;
  int wm = w >> 2, wn = w & 3;
  int m0 = blockIdx.x * 128;
  int n0 = blockIdx.y * 320;

  int ar = tid >> 2, ac = (tid & 3) * 8;
  const u16* Arow = A + (size_t)(m0 + ar)*KSTR + ac;
  bool bvld[3]; int brr[3], bcc[3];
  const u16* Brow[3];
  #pragma unroll
  for (int i = 0; i < 3; ++i){
    int ch = tid + i*512;
    bvld[i] = (ch < 1280);
    int r2 = bvld[i] ? (ch >> 2) : 0;
    brr[i] = r2; bcc[i] = (ch & 3) * 8;
    Brow[i] = W + (size_t)(n0 + r2)*KSTR + bcc[i];
  }

  u16x8 ra = *(const u16x8*)Arow;
  u16x8 rbv[3];
  #pragma unroll
  for (int i = 0; i < 3; ++i) if (bvld[i]) rbv[i] = *(const u16x8*)Brow[i];

  f32x4 zero = {0.f, 0.f, 0.f, 0.f};
  f32x4 acc[4][5];
  #pragma unroll
  for (int a = 0; a < 4; ++a)
    #pragma unroll
    for (int b = 0; b < 5; ++b) acc[a][b] = zero;

  for (int kk = 0; kk < 10; ++kk){
    __syncthreads();
    *(u16x8*)&Al[ar*40 + ac] = ra;
    #pragma unroll
    for (int i = 0; i < 3; ++i)
      if (bvld[i]) *(u16x8*)&Bl[brr[i]*40 + bcc[i]] = rbv[i];
    __syncthreads();
    if (kk < 9){
      int k1 = (kk+1)*32;
      ra = *(const u16x8*)(Arow + k1);
      #pragma unroll
      for (int i = 0; i < 3; ++i)
        if (bvld[i]) rbv[i] = *(const u16x8*)(Brow[i] + k1);
    }
    u16x8 av[4], bv[5];
    #pragma unroll
    for (int mt = 0; mt < 4; ++mt)
      av[mt] = *(const u16x8*)&Al[(wm*64 + mt*16 + lo)*40 + hi*8];
    #pragma unroll
    for (int nt = 0; nt < 5; ++nt)
      bv[nt] = *(const u16x8*)&Bl[(wn*80 + nt*16 + lo)*40 + hi*8];
    #pragma unroll
    for (int mt = 0; mt < 4; ++mt)
      #pragma unroll
      for (int nt = 0; nt < 5; ++nt)
        acc[mt][nt] = __builtin_amdgcn_mfma_f32_16x16x32_bf16(
            __builtin_bit_cast(bf16x8, av[mt]),
            __builtin_bit_cast(bf16x8, bv[nt]),
            acc[mt][nt], 0, 0, 0);
  }

  #pragma unroll
  for (int mt = 0; mt < 4; ++mt){
    #pragma unroll
    for (int nt = 0; nt < 5; ++nt){
      int col = n0 + wn*80 + nt*16 + lo;
      if (col < GG){
        float bsv = bias[col];
        int g = (col >= 450) ? 3 : (col >= 300) ? 2 : (col >= 150) ? 1 : 0;
        int cofs = (col - g*150)*4 + g;   // interleaved [jj][gate]
        #pragma unroll
        for (int r = 0; r < 4; ++r){
          int row = m0 + wm*64 + mt*16 + hi*4 + r;
          outp[(size_t)row*GSTR + cofs] = f2bf(acc[mt][nt][r] + bsv);
        }
      }
    }
  }
}

// ---------------- merged recurrence: blockIdx.z routes {L1 chunk A | L0 chunk B} ----------------
// 640 thr = 10 waves; wave w owns jj in [16w,16w+16); lane holds all 4 gates of its jj in-reg.
#define PREF(GB, TT)                                                            \
  {                                                                             \
    _Pragma("unroll")                                                           \
    for (int r = 0; r < 4; ++r){                                                \
      int Li = Lr[r];                                                           \
      int tt = ((TT) < Li) ? (TT) : (Li-1);                                     \
      int s_ = dir ? (Li-1-tt) : tt;                                            \
      int tok = (int)tks[(hi*4+r)*256 + s_];                                    \
      int rowi = isL1 ? (rowb[r] + s_) : tok;                                   \
      GB[r] = *(const u16x4*)(xg + (size_t)rowi*GSTR + jjc*4);                  \
    }                                                                           \
  }

#define REC_STEP(T, PB, GB)                                                     \
  {                                                                             \
    f32x4 acc0 = {0,0,0,0}, acc1 = {0,0,0,0}, acc2 = {0,0,0,0}, acc3 = {0,0,0,0}; \
    __builtin_amdgcn_s_setprio(1);                                              \
    _Pragma("unroll")                                                           \
    for (int ks = 0; ks < 5; ++ks){                                             \
      u16x8 a_ = *(const u16x8*)&hsm[PB][lo*168 + ks*32 + hi*8];                \
      acc0 = __builtin_amdgcn_mfma_f32_16x16x32_bf16(                           \
          __builtin_bit_cast(bf16x8, a_), __builtin_bit_cast(bf16x8, bw[0][ks]), acc0, 0,0,0); \
      acc1 = __builtin_amdgcn_mfma_f32_16x16x32_bf16(                           \
          __builtin_bit_cast(bf16x8, a_), __builtin_bit_cast(bf16x8, bw[1][ks]), acc1, 0,0,0); \
      acc2 = __builtin_amdgcn_mfma_f32_16x16x32_bf16(                           \
          __builtin_bit_cast(bf16x8, a_), __builtin_bit_cast(bf16x8, bw[2][ks]), acc2, 0,0,0); \
      acc3 = __builtin_amdgcn_mfma_f32_16x16x32_bf16(                           \
          __builtin_bit_cast(bf16x8, a_), __builtin_bit_cast(bf16x8, bw[3][ks]), acc3, 0,0,0); \
    }                                                                           \
    __builtin_amdgcn_s_setprio(0);                                              \
    _Pragma("unroll")                                                           \
    for (int r = 0; r < 4; ++r){                                                \
      if (jv && (T) < Lr[r]){                                                   \
        float pi = acc0[r] + bf2f(GB[r][0]);                                    \
        float pf = acc1[r] + bf2f(GB[r][1]);                                    \
        float pg = acc2[r] + bf2f(GB[r][2]);                                    \
        float po = acc3[r] + bf2f(GB[r][3]);                                    \
        float ig = fsig(pi), fg = fsig(pf), g2 = ftanh_(pg), og = fsig(po);     \
        float cc = fg*cst[r] + ig*g2;  cst[r] = cc;                             \
        float hn = og * ftanh_(cc);                                             \
        u16 hb = f2bf(hn);                                                      \
        hsm[(PB)^1][(hi*4+r)*168 + jj] = hb;                                    \
        if (!isL1){                                                             \
          int s_ = dir ? (Lr[r]-1-(T)) : (T);                                   \
          h1[(size_t)(rowb[r]+s_)*KSTR + dir*150 + jj] = hb;                    \
        } else {                                                                \
          bool isl = dir ? ((T)==0) : ((T)==Lr[r]-1);                           \
          if (isl) lastf[(size_t)bo2[r]*304 + dir*150 + jj] = hn;               \
        }                                                                       \
      }                                                                         \
    }                                                                           \
    if ((T)+2 < maxL){                                                          \
      PREF(GB, (T)+2)                                                           \
    }                                                                           \
    __builtin_amdgcn_sched_barrier(0);                                          \
    asm volatile("s_waitcnt lgkmcnt(0)" ::: "memory");                          \
    __builtin_amdgcn_s_barrier();                                               \
    __builtin_amdgcn_sched_barrier(0);                                          \
  }

__launch_bounds__(640, 3)
__global__ void k_recM(const u16* __restrict__ gF, const u16* __restrict__ gBf,
                       const u16* __restrict__ tF, const u16* __restrict__ tB,
                       const u16* __restrict__ Wh0F, const u16* __restrict__ Wh0B,
                       const u16* __restrict__ Wh1F, const u16* __restrict__ Wh1B,
                       const int* __restrict__ len, const int* __restrict__ perm,
                       const int* __restrict__ x,
                       u16* __restrict__ h1, float* __restrict__ lastf,
                       int coA, int coB, int mode0)
{
  const int isL1 = (blockIdx.z == 0) ? mode0 : 0;
  const int dir  = blockIdx.y;
  const int tile = blockIdx.x;
  const int co   = isL1 ? coA : coB;
  const u16* xg  = isL1 ? (dir ? gBf : gF) : (dir ? tB : tF);
  const u16* Whh = isL1 ? (dir ? Wh1B : Wh1F) : (dir ? Wh0B : Wh0F);

  __shared__ u16 hsm[2][16*168];   // bf16 h dbuf [16 samples][160 padK] stride 168
  __shared__ u16 tks[16*256];      // tokens
  __shared__ int Ls[16], rbL[16], boS[16];

  int tid = threadIdx.x;
  int l = tid & 63, w = tid >> 6;   // w = jj-group 0..9
  int lo = l & 15, hi = l >> 4;
  int jj = w*16 + lo;               // 0..159
  bool jv = (jj < HH);
  int jjc = jv ? jj : 0;

  // B fragments: acc tile g covers Whh rows g*150 + jj (row < 610 < 640, zero-padded)
  u16x8 bw[4][5];
  #pragma unroll
  for (int g = 0; g < 4; ++g)
    #pragma unroll
    for (int ks = 0; ks < 5; ++ks)
      bw[g][ks] = *(const u16x8*)(Whh + (size_t)(g*150 + jj)*WK + ks*32 + hi*8);

  for (int i = tid; i < 2*16*168; i += 640) ((u16*)hsm)[i] = 0;
  if (tid < 16){
    int b = perm[co + tile*16 + tid];
    Ls[tid]  = len[b];
    rbL[tid] = (tile*16 + tid)*SS;
    boS[tid] = b;
  }
  __syncthreads();
  for (int idx = tid; idx < 16*256; idx += 640){
    int i = idx >> 8, s = idx & 255;
    tks[idx] = (u16)x[boS[i]*SS + s];
  }
  __syncthreads();

  int maxL = Ls[15];
  int Lr[4], rowb[4], bo2[4];
  #pragma unroll
  for (int r = 0; r < 4; ++r){
    int i = hi*4 + r;
    Lr[r] = Ls[i]; rowb[r] = rbL[i]; bo2[r] = boS[i];
  }

  float cst[4] = {0.f, 0.f, 0.f, 0.f};
  u16x4 gA[4], gB[4];
  PREF(gA, 0)
  PREF(gB, 1)
  asm volatile("s_waitcnt lgkmcnt(0)" ::: "memory");
  __builtin_amdgcn_s_barrier();

  for (int t = 0; t < maxL; t += 2){
    REC_STEP(t, 0, gA)
    if (t + 1 < maxL){
      REC_STEP(t+1, 1, gB)
    }
  }
}

// ---------------- classifier head (fp32, float4): out = tanh(last@W1.T+b1)@W2.T+b2 ----------------
__global__ void k_cls(const float* __restrict__ lastf,
                      const float* __restrict__ W1, const float* __restrict__ b1,
                      const float* __restrict__ W2, const float* __restrict__ b2,
                      float* __restrict__ out)
{
  __shared__ float inb[8][304];
  __shared__ float mid[8][304];
  int r0 = blockIdx.x * 8, tid = threadIdx.x;
  for (int i = tid; i < 8*76; i += 256){
    int r = i / 76, c4 = i - r*76;
    ((f4*)&inb[r][0])[c4] = ((const f4*)(lastf + (size_t)(r0+r)*304))[c4];
  }
  __syncthreads();
  for (int item = tid; item < 2400; item += 256){
    int r = item / 300, c = item - r*300;
    const f4* wr = (const f4*)(W1 + (size_t)c*300);
    const f4* xr = (const f4*)&inb[r][0];
    f4 a0 = {0,0,0,0}, a1 = {0,0,0,0}, a2 = {0,0,0,0};
    for (int k = 0; k < 75; k += 3){
      a0 += xr[k]   * wr[k];
      a1 += xr[k+1] * wr[k+1];
      a2 += xr[k+2] * wr[k+2];
    }
    f4 s4 = a0 + a1 + a2;
    float a = s4[0] + s4[1] + s4[2] + s4[3] + b1[c];
    mid[r][c] = ftanh_(a);
  }
  __syncthreads();
  for (int item = tid; item < 2400; item += 256){
    int r = item / 300, c = item - r*300;
    const f4* wr = (const f4*)(W2 + (size_t)c*300);
    const f4* xr = (const f4*)&mid[r][0];
    f4 a0 = {0,0,0,0}, a1 = {0,0,0,0}, a2 = {0,0,0,0};
    for (int k = 0; k < 75; k += 3){
      a0 += xr[k]   * wr[k];
      a1 += xr[k+1] * wr[k+1];
      a2 += xr[k+2] * wr[k+2];
    }
    f4 s4 = a0 + a1 + a2;
    out[(size_t)(r0+r)*300 + c] = s4[0] + s4[1] + s4[2] + s4[3] + b2[c];
  }
}

extern "C" void kernel_launch(void* const* d_in, const int* in_sizes, int n_in,
                              void* d_out, int out_size, void* d_ws, size_t ws_size,
                              hipStream_t stream)
{
  const int*   x    = (const int*)d_in[0];
  const int*   mask = (const int*)d_in[1];
  const float* emb  = (const float*)d_in[2];
  const float* Wih[4] = {(const float*)d_in[3], (const float*)d_in[6],
                         (const float*)d_in[9], (const float*)d_in[12]};
  const float* Whh[4] = {(const float*)d_in[4], (const float*)d_in[7],
                         (const float*)d_in[10], (const float*)d_in[13]};
  const float* bs[4]  = {(const float*)d_in[5], (const float*)d_in[8],
                         (const float*)d_in[11], (const float*)d_in[14]};
  const float* W1 = (const float*)d_in[15];
  const float* b1 = (const float*)d_in[16];
  const float* W2 = (const float*)d_in[17];
  const float* b2 = (const float*)d_in[18];
  float* out = (float*)d_out;

  char* p = (char*)d_ws;
  auto alloc = [&](size_t bytes){ char* r = p; p += (bytes + 255) & ~(size_t)255; return r; };

  // fixed allocations (~70 MB incl. token->gate tables)
  u16 *WihP[4], *WhhP[4];
  for (int i = 0; i < 4; ++i){
    WihP[i] = (u16*)alloc(640*320*2);
    WhhP[i] = (u16*)alloc(640*160*2);
  }
  float* biasP[4];
  for (int i = 0; i < 4; ++i) biasP[i] = (float*)alloc(640*4);
  int* len  = (int*)alloc(1024*4);
  int* perm = (int*)alloc(1024*4);
  float* lastf = (float*)alloc((size_t)1024*304*4);
  u16* embP = (u16*)alloc((size_t)VPAD*KSTR*2);
  u16* tabF = (u16*)alloc((size_t)VPAD*GSTR*2);
  u16* tabB = (u16*)alloc((size_t)VPAD*GSTR*2);
  size_t fixed_end = (size_t)(p - (char*)d_ws);

  // variable: h1 (chunk) + TWO single-chunk gate buffers (both dirs)
  const size_t per_sample = (size_t)SS*KSTR*2 + 2*(size_t)SS*GSTR*2;  // 778240 B
  int nc = 32;
  const int cands[6] = {1, 2, 4, 8, 16, 32};
  for (int ci = 0; ci < 6; ++ci){
    size_t need = fixed_end + (size_t)(BB / cands[ci]) * per_sample + (1u<<20);
    if (need <= ws_size){ nc = cands[ci]; break; }
  }
  const int Bc = BB / nc;
  const int Mc = Bc * SS;

  u16* h1    = (u16*)alloc((size_t)Mc*KSTR*2);
  u16* gateF = (u16*)alloc((size_t)Mc*GSTR*2);
  u16* gateB = (u16*)alloc((size_t)Mc*GSTR*2);

  hipMemsetAsync(h1, 0, (size_t)Mc*KSTR*2, stream);   // pad cols 300..319 must be 0

  k_len <<<dim3(1024), dim3(256), 0, stream>>>(mask, len);
  k_sort<<<dim3(1),    dim3(1024),0, stream>>>(len, perm);

  PrepW pw;
  for (int i = 0; i < 4; ++i){
    pw.src[i] = Wih[i]; pw.dst[i] = WihP[i];
    pw.R[i] = GG; pw.C[i] = DD; pw.DR[i] = 640; pw.DC[i] = KSTR;
    pw.src[4+i] = Whh[i]; pw.dst[4+i] = WhhP[i];
    pw.R[4+i] = GG; pw.C[4+i] = HH; pw.DR[4+i] = 640; pw.DC[4+i] = WK;
  }
  k_prepw<<<dim3(800, 8), dim3(256), 0, stream>>>(pw);

  PrepB pb;
  for (int i = 0; i < 4; ++i){ pb.src[i] = bs[i]; pb.dst[i] = biasP[i]; }
  k_prepb<<<dim3(3, 4), dim3(256), 0, stream>>>(pb);

  k_prepemb<<<dim3((VPAD*KSTR + 255)/256), dim3(256), 0, stream>>>(emb, embP);

  // token -> layer-0 x-gate tables (both dirs), bias folded, interleaved layout
  k_gemm<<<dim3(VPAD/128, 2, 2), dim3(512), 0, stream>>>(embP, WihP[0], WihP[1],
                                                         biasP[0], biasP[1], tabF, tabB);

  // chained pipeline: L0(c0) | G(c0) | [L1(c)+L0(c+1)] G(c+1) ... | L1(last)
  k_recM<<<dim3(Bc/16, 2, 1), dim3(640), 0, stream>>>(gateF, gateB, tabF, tabB,
                                                      WhhP[0], WhhP[1], WhhP[2], WhhP[3],
                                                      len, perm, x, h1, lastf,
                                                      0, 0, /*mode0=*/0);
  k_gemm<<<dim3(Mc/128, 2, 2), dim3(512), 0, stream>>>(h1, WihP[2], WihP[3],
                                                       biasP[2], biasP[3], gateF, gateB);
  for (int c = 0; c < nc; ++c){
    if (c + 1 < nc){
      k_recM<<<dim3(Bc/16, 2, 2), dim3(640), 0, stream>>>(gateF, gateB, tabF, tabB,
                                                          WhhP[0], WhhP[1], WhhP[2], WhhP[3],
                                                          len, perm, x, h1, lastf,
                                                          c*Bc, (c+1)*Bc, /*mode0=*/1);
      k_gemm<<<dim3(Mc/128, 2, 2), dim3(512), 0, stream>>>(h1, WihP[2], WihP[3],
                                                           biasP[2], biasP[3], gateF, gateB);
    } else {
      k_recM<<<dim3(Bc/16, 2, 1), dim3(640), 0, stream>>>(gateF, gateB, tabF, tabB,
                                                          WhhP[0], WhhP[1], WhhP[2], WhhP[3],
                                                          len, perm, x, h1, lastf,
                                                          c*Bc, 0, /*mode0=*/1);
    }
  }

  k_cls<<<dim3(128), dim3(256), 0, stream>>>(lastf, W1, b1, W2, b2, out);
}

// Round 6
// 3482.916 us; speedup vs baseline: 2.3281x; 1.0469x over previous
//
#include <hip/hip_runtime.h>

typedef unsigned short u16;
typedef __bf16 bf16x8 __attribute__((ext_vector_type(8)));
typedef float f32x4 __attribute__((ext_vector_type(4)));
typedef float f4 __attribute__((ext_vector_type(4)));
typedef unsigned short u16x8 __attribute__((ext_vector_type(8)));
typedef unsigned short u16x4 __attribute__((ext_vector_type(4)));

#define BB 1024
#define SS 256
#define DD 300
#define HH 150
#define GG 600
#define VV 21257
#define VPAD 21376      // 167*128
#define KSTR 320        // padded K stride for h1 / emb table
#define GSTR 600        // gate row stride (u16), layout [jj][4 gates] interleaved
#define WK 160          // padded Whh K stride
#define L2E 1.442695041f
#define L2E2 2.885390082f

static __device__ __forceinline__ float bf2f(u16 u){
  unsigned v = ((unsigned)u) << 16;
  return __builtin_bit_cast(float, v);
}
static __device__ __forceinline__ u16 f2bf(float f){
  unsigned u = __builtin_bit_cast(unsigned, f);
  u = u + 0x7FFFu + ((u >> 16) & 1u);
  return (u16)(u >> 16);
}
// inputs PRE-SCALED by log2e (sig) / 2log2e (tanh)
static __device__ __forceinline__ float fsig2(float p){
  return __builtin_amdgcn_rcpf(1.0f + __builtin_amdgcn_exp2f(-p));
}
static __device__ __forceinline__ float ftanh2(float p){  // p = 2*log2e*x
  return 2.0f * __builtin_amdgcn_rcpf(1.0f + __builtin_amdgcn_exp2f(-p)) - 1.0f;
}

// ---------------- lengths from mask ----------------
__global__ void k_len(const int* __restrict__ mask, int* __restrict__ len){
  __shared__ int red[256];
  int b = blockIdx.x, t = threadIdx.x;
  red[t] = (mask[b*SS + t] != 0) ? 1 : 0;
  __syncthreads();
  for (int o = 128; o > 0; o >>= 1){
    if (t < o) red[t] += red[t+o];
    __syncthreads();
  }
  if (t == 0) len[b] = red[0];
}

// ---------------- deterministic rank sort by length (ascending) ----------------
__global__ void k_sort(const int* __restrict__ len, int* __restrict__ perm){
  __shared__ int L[1024];
  int b = threadIdx.x;
  int l = len[b];
  L[b] = l;
  __syncthreads();
  int r = 0;
  for (int j = 0; j < 1024; ++j){
    int lj = L[j];
    r += (lj < l) || (lj == l && j < b);
  }
  perm[r] = b;
}

// ---------------- weight pad/convert f32 -> bf16, gate-row pre-scale by log2e ----------------
struct PrepW {
  const float* src[8];
  u16* dst[8];
  int R[8], C[8], DR[8], DC[8];
};
__global__ void k_prepw(PrepW p){
  int z = blockIdx.y;
  int n = p.DR[z]*p.DC[z];
  for (int i = blockIdx.x*256 + threadIdx.x; i < n; i += 800*256){
    int r = i / p.DC[z], c = i - r*p.DC[z];
    float v = (r < p.R[z] && c < p.C[z]) ? p.src[z][r*p.C[z] + c] : 0.f;
    float sc = (r >= 300 && r < 450) ? L2E2 : L2E;   // g-gate rows get 2*log2e
    p.dst[z][i] = f2bf(v * sc);
  }
}
struct PrepB { const float* src[4]; float* dst[4]; };
__global__ void k_prepb(PrepB p){
  int z = blockIdx.y;
  int i = blockIdx.x*256 + threadIdx.x;
  if (i < 640){
    float v = (i < GG) ? p.src[z][i] : 0.f;
    float sc = (i >= 300 && i < 450) ? L2E2 : L2E;
    p.dst[z][i] = v * sc;
  }
}

// ---------------- embedding table pad/convert: [VPAD][KSTR] bf16, row 0 zeroed ----------------
__global__ void k_prepemb(const float* __restrict__ emb, u16* __restrict__ dst){
  long i = (long)blockIdx.x*256 + threadIdx.x;
  if (i >= (long)VPAD*KSTR) return;
  int r = (int)(i / KSTR), c = (int)(i - (long)r*KSTR);
  float v = (r >= 1 && r < VV && c < DD) ? emb[(size_t)r*DD + c] : 0.f;
  dst[i] = f2bf(v);
}

// ---------------- big GEMM: gates[m][jj*4+g] = bf16( sum_k A[m][k]*W[g*150+jj][k] + bias ) ----
__launch_bounds__(512, 2)
__global__ void k_gemm(const u16* __restrict__ A,
                       const u16* __restrict__ Wf, const u16* __restrict__ Wb,
                       const float* __restrict__ bsf, const float* __restrict__ bsb,
                       u16* __restrict__ of, u16* __restrict__ ob)
{
  const u16* W = blockIdx.z ? Wb : Wf;
  const float* bias = blockIdx.z ? bsb : bsf;
  u16* outp = blockIdx.z ? ob : of;

  __shared__ u16 Al[128*40];
  __shared__ u16 Bl[320*40];

  int tid = threadIdx.x;
  int l = tid & 63, w = tid >> 6;
  int lo = l & 15, hi = l >> 4;
  int wm = w >> 2, wn = w & 3;
  int m0 = blockIdx.x * 128;
  int n0 = blockIdx.y * 320;

  int ar = tid >> 2, ac = (tid & 3) * 8;
  const u16* Arow = A + (size_t)(m0 + ar)*KSTR + ac;
  bool bvld[3]; int brr[3], bcc[3];
  const u16* Brow[3];
  #pragma unroll
  for (int i = 0; i < 3; ++i){
    int ch = tid + i*512;
    bvld[i] = (ch < 1280);
    int r2 = bvld[i] ? (ch >> 2) : 0;
    brr[i] = r2; bcc[i] = (ch & 3) * 8;
    Brow[i] = W + (size_t)(n0 + r2)*KSTR + bcc[i];
  }

  u16x8 ra = *(const u16x8*)Arow;
  u16x8 rbv[3];
  #pragma unroll
  for (int i = 0; i < 3; ++i) if (bvld[i]) rbv[i] = *(const u16x8*)Brow[i];

  f32x4 zero = {0.f, 0.f, 0.f, 0.f};
  f32x4 acc[4][5];
  #pragma unroll
  for (int a = 0; a < 4; ++a)
    #pragma unroll
    for (int b = 0; b < 5; ++b) acc[a][b] = zero;

  for (int kk = 0; kk < 10; ++kk){
    __syncthreads();
    *(u16x8*)&Al[ar*40 + ac] = ra;
    #pragma unroll
    for (int i = 0; i < 3; ++i)
      if (bvld[i]) *(u16x8*)&Bl[brr[i]*40 + bcc[i]] = rbv[i];
    __syncthreads();
    if (kk < 9){
      int k1 = (kk+1)*32;
      ra = *(const u16x8*)(Arow + k1);
      #pragma unroll
      for (int i = 0; i < 3; ++i)
        if (bvld[i]) rbv[i] = *(const u16x8*)(Brow[i] + k1);
    }
    u16x8 av[4], bv[5];
    #pragma unroll
    for (int mt = 0; mt < 4; ++mt)
      av[mt] = *(const u16x8*)&Al[(wm*64 + mt*16 + lo)*40 + hi*8];
    #pragma unroll
    for (int nt = 0; nt < 5; ++nt)
      bv[nt] = *(const u16x8*)&Bl[(wn*80 + nt*16 + lo)*40 + hi*8];
    #pragma unroll
    for (int mt = 0; mt < 4; ++mt)
      #pragma unroll
      for (int nt = 0; nt < 5; ++nt)
        acc[mt][nt] = __builtin_amdgcn_mfma_f32_16x16x32_bf16(
            __builtin_bit_cast(bf16x8, av[mt]),
            __builtin_bit_cast(bf16x8, bv[nt]),
            acc[mt][nt], 0, 0, 0);
  }

  #pragma unroll
  for (int mt = 0; mt < 4; ++mt){
    #pragma unroll
    for (int nt = 0; nt < 5; ++nt){
      int col = n0 + wn*80 + nt*16 + lo;
      if (col < GG){
        float bsv = bias[col];
        int g = (col >= 450) ? 3 : (col >= 300) ? 2 : (col >= 150) ? 1 : 0;
        int cofs = (col - g*150)*4 + g;   // interleaved [jj][gate]
        #pragma unroll
        for (int r = 0; r < 4; ++r){
          int row = m0 + wm*64 + mt*16 + hi*4 + r;
          outp[(size_t)row*GSTR + cofs] = f2bf(acc[mt][nt][r] + bsv);
        }
      }
    }
  }
}

// ---------------- merged recurrence: blockIdx.z routes {L1 chunk A | L0 chunk B} ----------------
// 640 thr = 10 waves; wave w owns jj in [16w,16w+16); lane holds all 4 gates of its jj in-reg.
// depth-4 gate prefetch (4 static buffers, unroll-4 loop) — ~3 steps of load slack.
#define PREF(GB, TT)                                                            \
  {                                                                             \
    _Pragma("unroll")                                                           \
    for (int r = 0; r < 4; ++r){                                                \
      int Li = Lr[r];                                                           \
      int tt = ((TT) < Li) ? (TT) : (Li-1);                                     \
      int s_ = dir ? (Li-1-tt) : tt;                                            \
      int rowi;                                                                 \
      if (isL1) rowi = rowb[r] + s_;                                            \
      else      rowi = (int)tks[(hi*4+r)*256 + s_];                             \
      GB[r] = *(const u16x4*)(xg + (size_t)rowi*GSTR + jjc*4);                  \
    }                                                                           \
  }

#define REC_STEP(T, PB, GB)                                                     \
  {                                                                             \
    f32x4 acc0 = {0,0,0,0}, acc1 = {0,0,0,0}, acc2 = {0,0,0,0}, acc3 = {0,0,0,0}; \
    _Pragma("unroll")                                                           \
    for (int ks = 0; ks < 5; ++ks){                                             \
      u16x8 a_ = *(const u16x8*)&hsm[PB][lo*168 + ks*32 + hi*8];                \
      acc0 = __builtin_amdgcn_mfma_f32_16x16x32_bf16(                           \
          __builtin_bit_cast(bf16x8, a_), __builtin_bit_cast(bf16x8, bw[0][ks]), acc0, 0,0,0); \
      acc1 = __builtin_amdgcn_mfma_f32_16x16x32_bf16(                           \
          __builtin_bit_cast(bf16x8, a_), __builtin_bit_cast(bf16x8, bw[1][ks]), acc1, 0,0,0); \
      acc2 = __builtin_amdgcn_mfma_f32_16x16x32_bf16(                           \
          __builtin_bit_cast(bf16x8, a_), __builtin_bit_cast(bf16x8, bw[2][ks]), acc2, 0,0,0); \
      acc3 = __builtin_amdgcn_mfma_f32_16x16x32_bf16(                           \
          __builtin_bit_cast(bf16x8, a_), __builtin_bit_cast(bf16x8, bw[3][ks]), acc3, 0,0,0); \
    }                                                                           \
    _Pragma("unroll")                                                           \
    for (int r = 0; r < 4; ++r){                                                \
      if (jv && (T) < Lr[r]){                                                   \
        float pi = acc0[r] + bf2f(GB[r][0]);                                    \
        float pf = acc1[r] + bf2f(GB[r][1]);                                    \
        float pg = acc2[r] + bf2f(GB[r][2]);                                    \
        float po = acc3[r] + bf2f(GB[r][3]);                                    \
        float ig = fsig2(pi), fg = fsig2(pf), g2 = ftanh2(pg), og = fsig2(po);  \
        float cc = fg*cst[r] + ig*g2;  cst[r] = cc;                             \
        float hn = og * ftanh2(L2E2 * cc);                                      \
        u16 hb = f2bf(hn);                                                      \
        hsm[(PB)^1][(hi*4+r)*168 + jj] = hb;                                    \
        if (!isL1){                                                             \
          int s_ = dir ? (Lr[r]-1-(T)) : (T);                                   \
          h1[(size_t)(rowb[r]+s_)*KSTR + dir*150 + jj] = hb;                    \
        } else {                                                                \
          bool isl = dir ? ((T)==0) : ((T)==Lr[r]-1);                           \
          if (isl) lastf[(size_t)bo2[r]*304 + dir*150 + jj] = hn;               \
        }                                                                       \
      }                                                                         \
    }                                                                           \
    if ((T)+4 < maxL){                                                          \
      PREF(GB, (T)+4)                                                           \
    }                                                                           \
    __builtin_amdgcn_sched_barrier(0);                                          \
    asm volatile("s_waitcnt lgkmcnt(0)" ::: "memory");                          \
    __builtin_amdgcn_s_barrier();                                               \
    __builtin_amdgcn_sched_barrier(0);                                          \
  }

__launch_bounds__(640, 2)
__global__ void k_recM(const u16* __restrict__ gF, const u16* __restrict__ gBf,
                       const u16* __restrict__ tF, const u16* __restrict__ tB,
                       const u16* __restrict__ Wh0F, const u16* __restrict__ Wh0B,
                       const u16* __restrict__ Wh1F, const u16* __restrict__ Wh1B,
                       const int* __restrict__ len, const int* __restrict__ perm,
                       const int* __restrict__ x,
                       u16* __restrict__ h1, float* __restrict__ lastf,
                       int coA, int coB, int mode0)
{
  const int isL1 = (blockIdx.z == 0) ? mode0 : 0;
  const int dir  = blockIdx.y;
  const int tile = blockIdx.x;
  const int co   = isL1 ? coA : coB;
  const u16* xg  = isL1 ? (dir ? gBf : gF) : (dir ? tB : tF);
  const u16* Whh = isL1 ? (dir ? Wh1B : Wh1F) : (dir ? Wh0B : Wh0F);

  __shared__ u16 hsm[2][16*168];   // bf16 h dbuf [16 samples][160 padK] stride 168
  __shared__ u16 tks[16*256];      // tokens
  __shared__ int Ls[16], rbL[16], boS[16];

  int tid = threadIdx.x;
  int l = tid & 63, w = tid >> 6;   // w = jj-group 0..9
  int lo = l & 15, hi = l >> 4;
  int jj = w*16 + lo;               // 0..159
  bool jv = (jj < HH);
  int jjc = jv ? jj : 0;

  // B fragments: acc tile g covers Whh rows g*150 + jj (row < 610 < 640, zero-padded)
  u16x8 bw[4][5];
  #pragma unroll
  for (int g = 0; g < 4; ++g)
    #pragma unroll
    for (int ks = 0; ks < 5; ++ks)
      bw[g][ks] = *(const u16x8*)(Whh + (size_t)(g*150 + jj)*WK + ks*32 + hi*8);

  for (int i = tid; i < 2*16*168; i += 640) ((u16*)hsm)[i] = 0;
  if (tid < 16){
    int b = perm[co + tile*16 + tid];
    Ls[tid]  = len[b];
    rbL[tid] = (tile*16 + tid)*SS;
    boS[tid] = b;
  }
  __syncthreads();
  if (!isL1){
    for (int idx = tid; idx < 16*256; idx += 640){
      int i = idx >> 8, s = idx & 255;
      tks[idx] = (u16)x[boS[i]*SS + s];
    }
  }
  __syncthreads();

  int maxL = Ls[15];
  int Lr[4], rowb[4], bo2[4];
  #pragma unroll
  for (int r = 0; r < 4; ++r){
    int i = hi*4 + r;
    Lr[r] = Ls[i]; rowb[r] = rbL[i]; bo2[r] = boS[i];
  }

  float cst[4] = {0.f, 0.f, 0.f, 0.f};
  u16x4 g0[4], g1[4], g2b[4], g3[4];
  PREF(g0, 0)
  PREF(g1, 1)
  PREF(g2b, 2)
  PREF(g3, 3)

  for (int t = 0; t < maxL; t += 4){
    REC_STEP(t, 0, g0)
    if (t + 1 < maxL) REC_STEP(t+1, 1, g1)
    if (t + 2 < maxL) REC_STEP(t+2, 0, g2b)
    if (t + 3 < maxL) REC_STEP(t+3, 1, g3)
  }
}

// ---------------- classifier head (fp32, float4): out = tanh(last@W1.T+b1)@W2.T+b2 ----------------
__global__ void k_cls(const float* __restrict__ lastf,
                      const float* __restrict__ W1, const float* __restrict__ b1,
                      const float* __restrict__ W2, const float* __restrict__ b2,
                      float* __restrict__ out)
{
  __shared__ float inb[8][304];
  __shared__ float mid[8][304];
  int r0 = blockIdx.x * 8, tid = threadIdx.x;
  for (int i = tid; i < 8*76; i += 256){
    int r = i / 76, c4 = i - r*76;
    ((f4*)&inb[r][0])[c4] = ((const f4*)(lastf + (size_t)(r0+r)*304))[c4];
  }
  __syncthreads();
  for (int item = tid; item < 2400; item += 256){
    int r = item / 300, c = item - r*300;
    const f4* wr = (const f4*)(W1 + (size_t)c*300);
    const f4* xr = (const f4*)&inb[r][0];
    f4 a0 = {0,0,0,0}, a1 = {0,0,0,0}, a2 = {0,0,0,0};
    for (int k = 0; k < 75; k += 3){
      a0 += xr[k]   * wr[k];
      a1 += xr[k+1] * wr[k+1];
      a2 += xr[k+2] * wr[k+2];
    }
    f4 s4 = a0 + a1 + a2;
    float a = s4[0] + s4[1] + s4[2] + s4[3] + b1[c];
    // plain tanh (unscaled weights here)
    mid[r][c] = 2.0f * __builtin_amdgcn_rcpf(1.0f + __builtin_amdgcn_exp2f(-L2E2*a)) - 1.0f;
  }
  __syncthreads();
  for (int item = tid; item < 2400; item += 256){
    int r = item / 300, c = item - r*300;
    const f4* wr = (const f4*)(W2 + (size_t)c*300);
    const f4* xr = (const f4*)&mid[r][0];
    f4 a0 = {0,0,0,0}, a1 = {0,0,0,0}, a2 = {0,0,0,0};
    for (int k = 0; k < 75; k += 3){
      a0 += xr[k]   * wr[k];
      a1 += xr[k+1] * wr[k+1];
      a2 += xr[k+2] * wr[k+2];
    }
    f4 s4 = a0 + a1 + a2;
    out[(size_t)(r0+r)*300 + c] = s4[0] + s4[1] + s4[2] + s4[3] + b2[c];
  }
}

extern "C" void kernel_launch(void* const* d_in, const int* in_sizes, int n_in,
                              void* d_out, int out_size, void* d_ws, size_t ws_size,
                              hipStream_t stream)
{
  const int*   x    = (const int*)d_in[0];
  const int*   mask = (const int*)d_in[1];
  const float* emb  = (const float*)d_in[2];
  const float* Wih[4] = {(const float*)d_in[3], (const float*)d_in[6],
                         (const float*)d_in[9], (const float*)d_in[12]};
  const float* Whh[4] = {(const float*)d_in[4], (const float*)d_in[7],
                         (const float*)d_in[10], (const float*)d_in[13]};
  const float* bs[4]  = {(const float*)d_in[5], (const float*)d_in[8],
                         (const float*)d_in[11], (const float*)d_in[14]};
  const float* W1 = (const float*)d_in[15];
  const float* b1 = (const float*)d_in[16];
  const float* W2 = (const float*)d_in[17];
  const float* b2 = (const float*)d_in[18];
  float* out = (float*)d_out;

  char* p = (char*)d_ws;
  auto alloc = [&](size_t bytes){ char* r = p; p += (bytes + 255) & ~(size_t)255; return r; };

  // fixed allocations (~70 MB incl. token->gate tables)
  u16 *WihP[4], *WhhP[4];
  for (int i = 0; i < 4; ++i){
    WihP[i] = (u16*)alloc(640*320*2);
    WhhP[i] = (u16*)alloc(640*160*2);
  }
  float* biasP[4];
  for (int i = 0; i < 4; ++i) biasP[i] = (float*)alloc(640*4);
  int* len  = (int*)alloc(1024*4);
  int* perm = (int*)alloc(1024*4);
  float* lastf = (float*)alloc((size_t)1024*304*4);
  u16* embP = (u16*)alloc((size_t)VPAD*KSTR*2);
  u16* tabF = (u16*)alloc((size_t)VPAD*GSTR*2);
  u16* tabB = (u16*)alloc((size_t)VPAD*GSTR*2);
  size_t fixed_end = (size_t)(p - (char*)d_ws);

  // variable: h1 (chunk) + TWO single-chunk gate buffers (both dirs)
  const size_t per_sample = (size_t)SS*KSTR*2 + 2*(size_t)SS*GSTR*2;  // 778240 B
  int nc = 32;
  const int cands[6] = {1, 2, 4, 8, 16, 32};
  for (int ci = 0; ci < 6; ++ci){
    size_t need = fixed_end + (size_t)(BB / cands[ci]) * per_sample + (1u<<20);
    if (need <= ws_size){ nc = cands[ci]; break; }
  }
  const int Bc = BB / nc;
  const int Mc = Bc * SS;

  u16* h1    = (u16*)alloc((size_t)Mc*KSTR*2);
  u16* gateF = (u16*)alloc((size_t)Mc*GSTR*2);
  u16* gateB = (u16*)alloc((size_t)Mc*GSTR*2);

  hipMemsetAsync(h1, 0, (size_t)Mc*KSTR*2, stream);   // pad cols 300..319 must be 0

  k_len <<<dim3(1024), dim3(256), 0, stream>>>(mask, len);
  k_sort<<<dim3(1),    dim3(1024),0, stream>>>(len, perm);

  PrepW pw;
  for (int i = 0; i < 4; ++i){
    pw.src[i] = Wih[i]; pw.dst[i] = WihP[i];
    pw.R[i] = GG; pw.C[i] = DD; pw.DR[i] = 640; pw.DC[i] = KSTR;
    pw.src[4+i] = Whh[i]; pw.dst[4+i] = WhhP[i];
    pw.R[4+i] = GG; pw.C[4+i] = HH; pw.DR[4+i] = 640; pw.DC[4+i] = WK;
  }
  k_prepw<<<dim3(800, 8), dim3(256), 0, stream>>>(pw);

  PrepB pb;
  for (int i = 0; i < 4; ++i){ pb.src[i] = bs[i]; pb.dst[i] = biasP[i]; }
  k_prepb<<<dim3(3, 4), dim3(256), 0, stream>>>(pb);

  k_prepemb<<<dim3((VPAD*KSTR + 255)/256), dim3(256), 0, stream>>>(emb, embP);

  // token -> layer-0 x-gate tables (both dirs), bias folded, interleaved layout
  k_gemm<<<dim3(VPAD/128, 2, 2), dim3(512), 0, stream>>>(embP, WihP[0], WihP[1],
                                                         biasP[0], biasP[1], tabF, tabB);

  // chained pipeline: L0(c0) | G(c0) | [L1(c)+L0(c+1)] G(c+1) ... | L1(last)
  k_recM<<<dim3(Bc/16, 2, 1), dim3(640), 0, stream>>>(gateF, gateB, tabF, tabB,
                                                      WhhP[0], WhhP[1], WhhP[2], WhhP[3],
                                                      len, perm, x, h1, lastf,
                                                      0, 0, /*mode0=*/0);
  k_gemm<<<dim3(Mc/128, 2, 2), dim3(512), 0, stream>>>(h1, WihP[2], WihP[3],
                                                       biasP[2], biasP[3], gateF, gateB);
  for (int c = 0; c < nc; ++c){
    if (c + 1 < nc){
      k_recM<<<dim3(Bc/16, 2, 2), dim3(640), 0, stream>>>(gateF, gateB, tabF, tabB,
                                                          WhhP[0], WhhP[1], WhhP[2], WhhP[3],
                                                          len, perm, x, h1, lastf,
                                                          c*Bc, (c+1)*Bc, /*mode0=*/1);
      k_gemm<<<dim3(Mc/128, 2, 2), dim3(512), 0, stream>>>(h1, WihP[2], WihP[3],
                                                           biasP[2], biasP[3], gateF, gateB);
    } else {
      k_recM<<<dim3(Bc/16, 2, 1), dim3(640), 0, stream>>>(gateF, gateB, tabF, tabB,
                                                          WhhP[0], WhhP[1], WhhP[2], WhhP[3],
                                                          len, perm, x, h1, lastf,
                                                          c*Bc, 0, /*mode0=*/1);
    }
  }

  k_cls<<<dim3(128), dim3(256), 0, stream>>>(lastf, W1, b1, W2, b2, out);
}